// Round 6
// baseline (55.620 us; speedup 1.0000x reference)
//
#include <hip/hip_runtime.h>
#include <math.h>

// Affine warp augmentation (kornia-style warp_affine, bilinear, zeros padding,
// align_corners pixel coords). B=128, C=3, H=W=256, fp32.
//
// R6: 32x64 tiles, one (b,c,tile) per block.
//  - LDS 37*108*4 = 15.98 KB -> 8 blocks/CU = 32 waves/CU (100% occupancy;
//    R5 was 26.5 KB -> ~5 blocks -> 55%).
//  - PITCH=37 (odd): gather bank = (5*y0 + x0) % 32, coprime stride ->
//    ~2-way conflicts (free) instead of 8-way at PITCH=36 (stride 4 mod 32).
//    Staging writes are linear lds[j] -> stride-1, conflict-free.
//  - Inner loop: incremental sx/sy stepping in LDS-local coords (integer
//    frame shifts are exact in fp32; bilinear is continuous so ulp drift is
//    harmless), lerp-form blend, mad24 index. ~16 VALU + 2 ds_read2 + 1
//    nontemporal store per pixel.
//  - Zero-halo staging (R4/R5 scheme): out-of-image positions stage as 0,
//    inner loop needs no masks/clamps and reproduces zeros-padding exactly.

#define AUG_ANG 0.34906585039886590  // deg2rad(20)
#define AUG_MAX_T 6.0

#define TW 32
#define TH 64
#define PITCH 37       // staged row width in floats; odd => coprime bank walk
#define MAXROWS 108    // >= |i10|*31 + i11*63 + margin = 0.789*31+1.227*63+4

// One thread per batch element: build the 2x3 affine matrix exactly as the
// reference does, invert the 2x2 part, store {i00,i01,i10,i11,T13,T23}.
__global__ void TCR_params_kernel(const float* __restrict__ rnd,
                                  float* __restrict__ p,
                                  int B, int W, int H) {
    int b = blockIdx.x * blockDim.x + threadIdx.x;
    if (b >= B) return;
    double r01 = (double)rnd[b];
    double tx = 2.0 * AUG_MAX_T * r01 - AUG_MAX_T;
    double ty = tx;                       // same random tensor for all params
    double r  = 2.0 * AUG_ANG * r01 - AUG_ANG;
    double z  = 1.0;                      // MAX_Z == MIN_Z == 1
    double hx = r, hy = r;
    double a  = hx - r;
    double bb = hy + r;
    double cos_hx = cos(hx), cos_hy = cos(hy);
    double ca = cos(a),  sa = sin(a);
    double cb = cos(bb), sb = sin(bb);
    double T11 = z * ca / cos_hx;
    double T12 = z * sa / cos_hx;
    double T13 = ((double)W * cos_hx - (double)W * z * ca + 2.0 * tx * z * ca
                  - (double)H * z * sa + 2.0 * ty * z * sa) / (2.0 * cos_hx);
    double T21 = z * sb / cos_hy;
    double T22 = z * cb / cos_hy;
    double T23 = ((double)H * cos_hy - (double)W * z * cb + 2.0 * ty * z * cb
                  - (double)W * z * sb + 2.0 * tx * z * sb) / (2.0 * cos_hy);
    double det = T11 * T22 - T12 * T21;
    p[b * 6 + 0] = (float)( T22 / det);
    p[b * 6 + 1] = (float)(-T12 / det);
    p[b * 6 + 2] = (float)(-T21 / det);
    p[b * 6 + 3] = (float)( T11 / det);
    p[b * 6 + 4] = (float)T13;
    p[b * 6 + 5] = (float)T23;
}

__global__ __launch_bounds__(256) void TCR_warp_kernel(
        const float* __restrict__ img, const float* __restrict__ p,
        float* __restrict__ out, int H, int W,
        int tilesX, int nTile, int nT, int useSwz) {
    __shared__ float lds[MAXROWS * PITCH + 2];

    const int tid = (int)threadIdx.x;
    int i = (int)blockIdx.x;
    int b, t;
    if (useSwz) {   // keep all (channel,tile) blocks of one image on one XCD
        int xcd = i & 7;
        int r   = i >> 3;
        b = xcd + 8 * (r / nT);
        t = r % nT;
    } else {
        b = i / nT;
        t = i % nT;
    }
    const int c  = t / nTile;        // channel
    const int tt = t - c * nTile;    // tile index
    const int tileY = tt / tilesX, tileX = tt - tileY * tilesX;
    const int tx0 = tileX * TW, ty0 = tileY * TH;
    const int tx1 = min(tx0 + TW - 1, W - 1);
    const int ty1 = min(ty0 + TH - 1, H - 1);

    const float i00 = p[b * 6 + 0];
    const float i01 = p[b * 6 + 1];
    const float i10 = p[b * 6 + 2];
    const float i11 = p[b * 6 + 3];
    const float T13 = p[b * 6 + 4];
    const float T23 = p[b * 6 + 5];

    // Unclamped source bbox from the 4 tile corners (affine => corners bound
    // interior; +/-1 margin absorbs fp rounding).
    const float cx0 = (float)tx0 - T13, cx1 = (float)tx1 - T13;
    const float cy0 = (float)ty0 - T23, cy1 = (float)ty1 - T23;
    const float sxA = i00 * cx0 + i01 * cy0, sxB = i00 * cx1 + i01 * cy0;
    const float sxC = i00 * cx0 + i01 * cy1, sxD = i00 * cx1 + i01 * cy1;
    const float syA = i10 * cx0 + i11 * cy0, syB = i10 * cx1 + i11 * cy0;
    const float syC = i10 * cx0 + i11 * cy1, syD = i10 * cx1 + i11 * cy1;
    const float sxmin = fminf(fminf(sxA, sxB), fminf(sxC, sxD));
    const float symin = fminf(fminf(syA, syB), fminf(syC, syD));
    const float symax = fmaxf(fmaxf(syA, syB), fmaxf(syC, syD));
    const int xs0 = (int)floorf(sxmin) - 1;
    const int ys0 = (int)floorf(symin) - 1;
    const int ys1 = min((int)floorf(symax) + 2, ys0 + MAXROWS - 1);
    const int hs = ys1 - ys0 + 1;

    const size_t plane = (size_t)H * W;
    const float* pl = img + (size_t)b * 3 * plane + (size_t)c * plane;

    // --- stage rows [ys0, ys1] x cols [xs0, xs0+PITCH) with zero-halo.
    // Linear lds[j] writes: stride-1, conflict-free. Loads coalesced.
    {
        const int total = hs * PITCH;
        for (int j = tid; j < total; j += 256) {
            const unsigned ju = (unsigned)j;
            const int ry = (int)(ju / PITCH);          // const-div -> mul_hi
            const int rx = (int)(ju - (unsigned)ry * PITCH);
            const int gy = ys0 + ry;
            const int gx = xs0 + rx;
            const int gyc = min(max(gy, 0), H - 1);    // clamped addr
            const int gxc = min(max(gx, 0), W - 1);
            const float f = pl[(size_t)gyc * W + gxc];
            const bool ok = ((unsigned)gx < (unsigned)W) &
                            ((unsigned)gy < (unsigned)H);
            lds[j] = ok ? f : 0.0f;
        }
    }
    __syncthreads();

    // --- compute: thread (xl = tid&31, yl = tid>>5), 8 y-steps of stride 8.
    const int xl = tid & 31;
    const int yl = tid >> 5;
    const int x = tx0 + xl;
    if (x > tx1) return;

    const float dx  = (float)x - T13;
    const float dy0 = (float)(ty0 + yl) - T23;
    // LDS-local coords: integer frame shift is exact in fp32.
    float sxl = i00 * dx + i01 * dy0 - (float)xs0;
    float syl = i10 * dx + i11 * dy0 - (float)ys0;
    const float dsx = 8.0f * i01;
    const float dsy = 8.0f * i11;

    float* po = out + (size_t)b * 3 * plane + (size_t)c * plane
                    + (size_t)(ty0 + yl) * W + x;

    #pragma unroll
    for (int k = 0; k < TH / 8; ++k) {
        const int y = ty0 + yl + 8 * k;
        if (y > ty1) break;              // wave-uniform for full tiles
        const float x0f = floorf(sxl);
        const float y0f = floorf(syl);
        const float wx = sxl - x0f;
        const float wy = syl - y0f;
        const int x0 = (int)x0f;         // >= 1 by construction
        const int y0 = (int)y0f;

        const int iA = y0 * PITCH + x0;  // mad24
        const float v00 = lds[iA];
        const float v01 = lds[iA + 1];
        const float v10 = lds[iA + PITCH];
        const float v11 = lds[iA + PITCH + 1];

        const float top = v00 + wx * (v01 - v00);
        const float bot = v10 + wx * (v11 - v10);
        const float v   = top + wy * (bot - top);
        __builtin_nontemporal_store(v, po);

        po  += 8 * W;
        sxl += dsx;
        syl += dsy;
    }
}

extern "C" void kernel_launch(void* const* d_in, const int* in_sizes, int n_in,
                              void* d_out, int out_size, void* d_ws, size_t ws_size,
                              hipStream_t stream) {
    const float* img = (const float*)d_in[0];
    const float* rnd = (const float*)d_in[1];
    float* out = (float*)d_out;
    float* params = (float*)d_ws;

    const int B = in_sizes[1];            // 128
    const int C = 3;
    const int total = in_sizes[0];        // B*C*H*W
    const int HW = total / (B * C);       // 65536
    int W = 256;                          // square images
    while (W * W > HW) W >>= 1;
    const int H = HW / W;

    TCR_params_kernel<<<(B + 127) / 128, 128, 0, stream>>>(rnd, params, B, W, H);

    const int tilesX = (W + TW - 1) / TW;
    const int tilesY = (H + TH - 1) / TH;
    const int nTile = tilesX * tilesY;    // 32
    const int nT = C * nTile;             // 96 blocks per image
    const int useSwz = (B % 8 == 0) ? 1 : 0;
    dim3 grid(B * nT);
    TCR_warp_kernel<<<grid, 256, 0, stream>>>(img, params, out, H, W,
                                              tilesX, nTile, nT, useSwz);
}

// Round 7
// 43.450 us; speedup vs baseline: 1.2801x; 1.2801x over previous
//
#include <hip/hip_runtime.h>
#include <math.h>

// Affine warp augmentation (kornia-style warp_affine, bilinear, zeros padding,
// align_corners pixel coords). B=128, C=3, H=W=256, fp32.
//
// R7: VALU-diet version of R6 (R6 was VALU-bound on staging + setup).
//  - i01 == 0 EXACTLY for this parameter family (a = hx - r = 0 identically,
//    in both reference fp32 and our fp64): sx/x0/wx are hoisted out of the
//    y-loop. Inner loop ~11 VALU + 2 ds_read2 + 1 store per pixel.
//  - Per-(b,tile) bbox {xs0(4-aligned), ys0, hs} precomputed in the params
//    kernel; warp-kernel setup is just a few loads + shifts.
//  - 3D grid (B, nTile, C): no integer divides in the hot kernel; and since
//    gridDim.x = 128 = 0 mod 8, linear dispatch order pins all blocks of
//    image b to XCD b%8 automatically (replaces explicit swizzle).
//  - Staging via float4 (W%4==0 required; true here): fast path for fully
//    interior bbox (no masks/clamps), slow path masks whole 4-slots
//    (uniform validity since xs0 and W are 4-aligned). Zero-halo preserved:
//    inner loop stays mask-free and reproduces zeros-padding exactly.
//  - PITCH=41 (odd): gather bank stride = 1 + 41*i10 mod 32 ~ stride-1 at
//    the angle extremes; LDS 41*108*4 ~ 17.7 KB -> 8 blocks/CU (32 waves).

#define AUG_ANG 0.34906585039886590  // deg2rad(20)
#define AUG_MAX_T 6.0

#define TW 32
#define TH 64
#define PITCH 41       // LDS row pitch (floats), odd
#define MAXROWS 108    // >= |i10|*31 + i11*63 + 5 = 24.5+77.3+5
#define SLOTS 10       // staged float4 slots per row (40 floats >= ws 38)

// One thread per (b, tile): builds the per-b affine params (thread with
// tile==0 writes them) and the per-(b,tile) source bbox.
__global__ void TCR_params_kernel(const float* __restrict__ rnd,
                                  float* __restrict__ p,
                                  int4* __restrict__ bb,
                                  int B, int W, int H,
                                  int tilesX, int nTile) {
    const int idx = blockIdx.x * blockDim.x + threadIdx.x;
    if (idx >= B * nTile) return;
    const int b = idx / nTile;
    const int t = idx - b * nTile;

    double r01 = (double)rnd[b];
    double tx = 2.0 * AUG_MAX_T * r01 - AUG_MAX_T;
    double ty = tx;                       // same random tensor for all params
    double r  = 2.0 * AUG_ANG * r01 - AUG_ANG;
    double z  = 1.0;                      // MAX_Z == MIN_Z == 1
    double hx = r, hy = r;
    double a  = hx - r;                   // == 0 exactly
    double bbang = hy + r;
    double cos_hx = cos(hx), cos_hy = cos(hy);
    double ca = cos(a),  sa = sin(a);
    double cb = cos(bbang), sb = sin(bbang);
    double T11 = z * ca / cos_hx;
    double T12 = z * sa / cos_hx;
    double T13 = ((double)W * cos_hx - (double)W * z * ca + 2.0 * tx * z * ca
                  - (double)H * z * sa + 2.0 * ty * z * sa) / (2.0 * cos_hx);
    double T21 = z * sb / cos_hy;
    double T22 = z * cb / cos_hy;
    double T23 = ((double)H * cos_hy - (double)W * z * cb + 2.0 * ty * z * cb
                  - (double)W * z * sb + 2.0 * tx * z * sb) / (2.0 * cos_hy);
    double det = T11 * T22 - T12 * T21;
    const float i00 = (float)( T22 / det);
    const float i01 = (float)(-T12 / det);   // == +/-0
    const float i10 = (float)(-T21 / det);
    const float i11 = (float)( T11 / det);
    const float f13 = (float)T13;
    const float f23 = (float)T23;

    if (t == 0) {
        p[b * 6 + 0] = i00;
        p[b * 6 + 1] = i01;
        p[b * 6 + 2] = i10;
        p[b * 6 + 3] = i11;
        p[b * 6 + 4] = f13;
        p[b * 6 + 5] = f23;
    }

    // bbox for tile t (float corner math, same scheme as R4-R6; +/-1 margins)
    const int tileY = t / tilesX, tileX = t - tileY * tilesX;
    const int tx0 = tileX * TW, ty0 = tileY * TH;
    const int tx1 = min(tx0 + TW - 1, W - 1);
    const int ty1 = min(ty0 + TH - 1, H - 1);
    const float cx0 = (float)tx0 - f13, cx1 = (float)tx1 - f13;
    const float cy0 = (float)ty0 - f23, cy1 = (float)ty1 - f23;
    const float sxA = i00 * cx0 + i01 * cy0, sxB = i00 * cx1 + i01 * cy0;
    const float sxC = i00 * cx0 + i01 * cy1, sxD = i00 * cx1 + i01 * cy1;
    const float syA = i10 * cx0 + i11 * cy0, syB = i10 * cx1 + i11 * cy0;
    const float syC = i10 * cx0 + i11 * cy1, syD = i10 * cx1 + i11 * cy1;
    const float sxmin = fminf(fminf(sxA, sxB), fminf(sxC, sxD));
    const float symin = fminf(fminf(syA, syB), fminf(syC, syD));
    const float symax = fmaxf(fmaxf(syA, syB), fmaxf(syC, syD));
    const int xs0 = ((int)floorf(sxmin) - 1) & ~3;     // 4-aligned down
    const int ys0 = (int)floorf(symin) - 1;
    const int ys1 = min((int)floorf(symax) + 2, ys0 + MAXROWS - 1);
    int4 v; v.x = xs0; v.y = ys0; v.z = ys1 - ys0 + 1; v.w = 0;
    bb[idx] = v;
}

// Grid: (B, nTile, C). Block: 256 threads.
__global__ __launch_bounds__(256) void TCR_warp_kernel(
        const float* __restrict__ img, const float* __restrict__ p,
        const int4* __restrict__ bb, float* __restrict__ out,
        int H, int W, int tilesXShift) {
    __shared__ float lds[MAXROWS * PITCH + 2];

    const int tid = (int)threadIdx.x;
    const int b = (int)blockIdx.x;
    const int t = (int)blockIdx.y;
    const int c = (int)blockIdx.z;
    const int nTile = (int)gridDim.y;
    const int tileY = t >> tilesXShift;
    const int tileX = t - (tileY << tilesXShift);
    const int tx0 = tileX * TW, ty0 = tileY * TH;

    const int4 box = bb[b * nTile + t];
    const int xs0 = box.x, ys0 = box.y, hs = box.z;

    const float i00 = p[b * 6 + 0];
    const float i10 = p[b * 6 + 2];
    const float i11 = p[b * 6 + 3];
    const float T13 = p[b * 6 + 4];
    const float T23 = p[b * 6 + 5];

    const size_t plane = (size_t)H * W;
    const float* pl = img + ((size_t)b * 3 + c) * plane;

    // --- stage rows [ys0, ys0+hs) x cols [xs0, xs0+40) with zero-halo ---
    const int nTask = hs * SLOTS;
    const bool fast = (xs0 >= 0) & (xs0 + 4 * SLOTS <= W) &
                      (ys0 >= 0) & (ys0 + hs <= H);
    if (fast) {
        for (int j = tid; j < nTask; j += 256) {
            const int ry = (int)((unsigned)j / SLOTS);   // literal -> magic mul
            const int rp = j - ry * SLOTS;
            const float4 f =
                *(const float4*)(pl + (size_t)(ys0 + ry) * W + xs0 + 4 * rp);
            const int o = ry * PITCH + 4 * rp;
            lds[o] = f.x; lds[o + 1] = f.y; lds[o + 2] = f.z; lds[o + 3] = f.w;
        }
    } else {
        for (int j = tid; j < nTask; j += 256) {
            const int ry = (int)((unsigned)j / SLOTS);
            const int rp = j - ry * SLOTS;
            const int gy = ys0 + ry;
            const int gx = xs0 + 4 * rp;
            const int gyc = min(max(gy, 0), H - 1);
            const int gxc = min(max(gx, 0), W - 4);
            const float4 f = *(const float4*)(pl + (size_t)gyc * W + gxc);
            // whole-slot validity: xs0 and W are multiples of 4, so a slot is
            // fully inside or fully outside in x.
            const bool ok = ((unsigned)gy < (unsigned)H) &
                            ((unsigned)gx < (unsigned)W);
            const int o = ry * PITCH + 4 * rp;
            lds[o]     = ok ? f.x : 0.0f;
            lds[o + 1] = ok ? f.y : 0.0f;
            lds[o + 2] = ok ? f.z : 0.0f;
            lds[o + 3] = ok ? f.w : 0.0f;
        }
    }
    __syncthreads();

    // --- compute: thread (xl = tid&31, yl = tid>>5), 8 y-steps of stride 8.
    const int xl = tid & 31;
    const int yl = tid >> 5;
    const int x = tx0 + xl;
    const int ybase = ty0 + yl;

    const float dx = (float)x - T13;
    // i01 == 0 exactly (a = hx - r = 0): sx is y-invariant -> hoist x-path.
    const float sxl = i00 * dx - (float)xs0;
    const float x0f = floorf(sxl);
    const float wx = sxl - x0f;
    const int x0 = (int)x0f;

    float syl = i10 * dx + i11 * ((float)ybase - T23) - (float)ys0;
    const float dsy = 8.0f * i11;

    float* po = out + ((size_t)b * 3 + c) * plane + (size_t)ybase * W + x;

    if ((tx0 + TW <= W) & (ty0 + TH <= H)) {   // full tile (always, here)
        #pragma unroll
        for (int k = 0; k < TH / 8; ++k) {
            const float y0f = floorf(syl);
            const float wy = syl - y0f;
            const int y0 = (int)y0f;
            const int iA = y0 * PITCH + x0;
            const float v00 = lds[iA];
            const float v01 = lds[iA + 1];
            const float v10 = lds[iA + PITCH];
            const float v11 = lds[iA + PITCH + 1];
            const float top = v00 + wx * (v01 - v00);
            const float bot = v10 + wx * (v11 - v10);
            __builtin_nontemporal_store(top + wy * (bot - top), po);
            po  += 8 * W;
            syl += dsy;
        }
    } else {                                   // partial tile (generality)
        if (x >= W) return;
        #pragma unroll
        for (int k = 0; k < TH / 8; ++k) {
            const int y = ybase + 8 * k;
            if (y >= H) break;
            const float y0f = floorf(syl);
            const float wy = syl - y0f;
            const int y0 = (int)y0f;
            const int iA = y0 * PITCH + x0;
            const float v00 = lds[iA];
            const float v01 = lds[iA + 1];
            const float v10 = lds[iA + PITCH];
            const float v11 = lds[iA + PITCH + 1];
            const float top = v00 + wx * (v01 - v00);
            const float bot = v10 + wx * (v11 - v10);
            __builtin_nontemporal_store(top + wy * (bot - top), po);
            po  += 8 * W;
            syl += dsy;
        }
    }
}

extern "C" void kernel_launch(void* const* d_in, const int* in_sizes, int n_in,
                              void* d_out, int out_size, void* d_ws, size_t ws_size,
                              hipStream_t stream) {
    const float* img = (const float*)d_in[0];
    const float* rnd = (const float*)d_in[1];
    float* out = (float*)d_out;
    float* params = (float*)d_ws;

    const int B = in_sizes[1];            // 128
    const int C = 3;
    const int total = in_sizes[0];        // B*C*H*W
    const int HW = total / (B * C);       // 65536
    int W = 256;                          // square images
    while (W * W > HW) W >>= 1;
    const int H = HW / W;

    const int tilesX = (W + TW - 1) / TW;     // 8 (pow2 for W=256)
    const int tilesY = (H + TH - 1) / TH;     // 4
    const int nTile = tilesX * tilesY;        // 32
    int tilesXShift = 0;
    while ((1 << tilesXShift) < tilesX) ++tilesXShift;

    // ws layout: params (B*6 floats) | bbox (B*nTile int4), 16B-aligned
    int4* bbox = (int4*)((char*)d_ws + ((B * 6 * sizeof(float) + 15) & ~15));

    const int nPar = B * nTile;
    TCR_params_kernel<<<(nPar + 255) / 256, 256, 0, stream>>>(
        rnd, params, bbox, B, W, H, tilesX, nTile);

    dim3 grid(B, nTile, C);
    TCR_warp_kernel<<<grid, 256, 0, stream>>>(img, params, bbox, out,
                                              H, W, tilesXShift);
}

// Round 8
// 42.454 us; speedup vs baseline: 1.3101x; 1.0235x over previous
//
#include <hip/hip_runtime.h>
#include <math.h>

// Affine warp augmentation (kornia-style warp_affine, bilinear, zeros padding,
// align_corners pixel coords). B=128, C=3, H=W=256, fp32.
//
// R8: LDS-pipe diet (R7 was LDS-pipe bound: ~28us/CU of ds cycles at 43us).
//  - PITCH=64: gather bank = (64*y0+x0)%32 = x0%32, and x0 stride/lane =
//    i00 = cos r in [0.94,1] -> banks ~consecutive for EVERY angle. Removes
//    the 8 cy/instr data-dependent conflict penalty (6.46M cy at R7).
//  - PITCH%4==0 -> staging writes are single ds_write_b128 per 4-float slot
//    (R7's PITCH=41 forced 4x ds_write_b32).
//  - LDS 64*108*4 = 27.6 KB -> 5 blocks/CU (accepted occupancy trade).
//  - Everything else from R7 kept: i01==0 exactly (a = hx-r = 0) -> sx/x0/wx
//    hoisted out of the y-loop; per-(b,tile) bbox precomputed in params
//    kernel; 3D grid (B,nTile,C) -> no divides, implicit XCD pinning
//    (gridDim.x=128 = 0 mod 8); float4 zero-halo staging with fast interior
//    path; mask-free bilinear inner loop (zero-halo reproduces zeros-padding
//    exactly); nontemporal stores.

#define AUG_ANG 0.34906585039886590  // deg2rad(20)
#define AUG_MAX_T 6.0

#define TW 32
#define TH 64
#define PITCH 64       // power-of-2: bank = x0 % 32 (y0 vanishes); b128-aligned
#define MAXROWS 108    // >= |i10|*31 + i11*63 + 5 = 24.5+77.3+5
#define SLOTS 10       // staged float4 slots per row (40 floats >= ws 38)

// One thread per (b, tile): builds the per-b affine params (thread with
// tile==0 writes them) and the per-(b,tile) source bbox.
__global__ void TCR_params_kernel(const float* __restrict__ rnd,
                                  float* __restrict__ p,
                                  int4* __restrict__ bb,
                                  int B, int W, int H,
                                  int tilesX, int nTile) {
    const int idx = blockIdx.x * blockDim.x + threadIdx.x;
    if (idx >= B * nTile) return;
    const int b = idx / nTile;
    const int t = idx - b * nTile;

    double r01 = (double)rnd[b];
    double tx = 2.0 * AUG_MAX_T * r01 - AUG_MAX_T;
    double ty = tx;                       // same random tensor for all params
    double r  = 2.0 * AUG_ANG * r01 - AUG_ANG;
    double z  = 1.0;                      // MAX_Z == MIN_Z == 1
    double hx = r, hy = r;
    double a  = hx - r;                   // == 0 exactly
    double bbang = hy + r;
    double cos_hx = cos(hx), cos_hy = cos(hy);
    double ca = cos(a),  sa = sin(a);
    double cb = cos(bbang), sb = sin(bbang);
    double T11 = z * ca / cos_hx;
    double T12 = z * sa / cos_hx;
    double T13 = ((double)W * cos_hx - (double)W * z * ca + 2.0 * tx * z * ca
                  - (double)H * z * sa + 2.0 * ty * z * sa) / (2.0 * cos_hx);
    double T21 = z * sb / cos_hy;
    double T22 = z * cb / cos_hy;
    double T23 = ((double)H * cos_hy - (double)W * z * cb + 2.0 * ty * z * cb
                  - (double)W * z * sb + 2.0 * tx * z * sb) / (2.0 * cos_hy);
    double det = T11 * T22 - T12 * T21;
    const float i00 = (float)( T22 / det);
    const float i01 = (float)(-T12 / det);   // == +/-0
    const float i10 = (float)(-T21 / det);
    const float i11 = (float)( T11 / det);
    const float f13 = (float)T13;
    const float f23 = (float)T23;

    if (t == 0) {
        p[b * 6 + 0] = i00;
        p[b * 6 + 1] = i01;
        p[b * 6 + 2] = i10;
        p[b * 6 + 3] = i11;
        p[b * 6 + 4] = f13;
        p[b * 6 + 5] = f23;
    }

    // bbox for tile t (float corner math, +/-1 margins; corners bound the
    // interior of an affine map)
    const int tileY = t / tilesX, tileX = t - tileY * tilesX;
    const int tx0 = tileX * TW, ty0 = tileY * TH;
    const int tx1 = min(tx0 + TW - 1, W - 1);
    const int ty1 = min(ty0 + TH - 1, H - 1);
    const float cx0 = (float)tx0 - f13, cx1 = (float)tx1 - f13;
    const float cy0 = (float)ty0 - f23, cy1 = (float)ty1 - f23;
    const float sxA = i00 * cx0 + i01 * cy0, sxB = i00 * cx1 + i01 * cy0;
    const float sxC = i00 * cx0 + i01 * cy1, sxD = i00 * cx1 + i01 * cy1;
    const float syA = i10 * cx0 + i11 * cy0, syB = i10 * cx1 + i11 * cy0;
    const float syC = i10 * cx0 + i11 * cy1, syD = i10 * cx1 + i11 * cy1;
    const float sxmin = fminf(fminf(sxA, sxB), fminf(sxC, sxD));
    const float symin = fminf(fminf(syA, syB), fminf(syC, syD));
    const float symax = fmaxf(fmaxf(syA, syB), fmaxf(syC, syD));
    const int xs0 = ((int)floorf(sxmin) - 1) & ~3;     // 4-aligned down
    const int ys0 = (int)floorf(symin) - 1;
    const int ys1 = min((int)floorf(symax) + 2, ys0 + MAXROWS - 1);
    int4 v; v.x = xs0; v.y = ys0; v.z = ys1 - ys0 + 1; v.w = 0;
    bb[idx] = v;
}

// Grid: (B, nTile, C). Block: 256 threads.
__global__ __launch_bounds__(256) void TCR_warp_kernel(
        const float* __restrict__ img, const float* __restrict__ p,
        const int4* __restrict__ bb, float* __restrict__ out,
        int H, int W, int tilesXShift) {
    __shared__ float lds[MAXROWS * PITCH + 4];

    const int tid = (int)threadIdx.x;
    const int b = (int)blockIdx.x;
    const int t = (int)blockIdx.y;
    const int c = (int)blockIdx.z;
    const int nTile = (int)gridDim.y;
    const int tileY = t >> tilesXShift;
    const int tileX = t - (tileY << tilesXShift);
    const int tx0 = tileX * TW, ty0 = tileY * TH;

    const int4 box = bb[b * nTile + t];
    const int xs0 = box.x, ys0 = box.y, hs = box.z;

    const float i00 = p[b * 6 + 0];
    const float i10 = p[b * 6 + 2];
    const float i11 = p[b * 6 + 3];
    const float T13 = p[b * 6 + 4];
    const float T23 = p[b * 6 + 5];

    const size_t plane = (size_t)H * W;
    const float* pl = img + ((size_t)b * 3 + c) * plane;

    // --- stage rows [ys0, ys0+hs) x cols [xs0, xs0+40) with zero-halo.
    // One ds_write_b128 per slot (o = ry*64 + 4*rp is 16B-aligned).
    const int nTask = hs * SLOTS;
    const bool fast = (xs0 >= 0) & (xs0 + 4 * SLOTS <= W) &
                      (ys0 >= 0) & (ys0 + hs <= H);
    if (fast) {
        for (int j = tid; j < nTask; j += 256) {
            const int ry = (int)((unsigned)j / SLOTS);   // literal -> magic mul
            const int rp = j - ry * SLOTS;
            const float4 f =
                *(const float4*)(pl + (size_t)(ys0 + ry) * W + xs0 + 4 * rp);
            *(float4*)&lds[(ry << 6) + 4 * rp] = f;
        }
    } else {
        for (int j = tid; j < nTask; j += 256) {
            const int ry = (int)((unsigned)j / SLOTS);
            const int rp = j - ry * SLOTS;
            const int gy = ys0 + ry;
            const int gx = xs0 + 4 * rp;
            const int gyc = min(max(gy, 0), H - 1);
            const int gxc = min(max(gx, 0), W - 4);
            float4 f = *(const float4*)(pl + (size_t)gyc * W + gxc);
            // whole-slot validity: xs0 and W are multiples of 4, so a slot is
            // fully inside or fully outside in x.
            const bool ok = ((unsigned)gy < (unsigned)H) &
                            ((unsigned)gx < (unsigned)W);
            f.x = ok ? f.x : 0.0f;
            f.y = ok ? f.y : 0.0f;
            f.z = ok ? f.z : 0.0f;
            f.w = ok ? f.w : 0.0f;
            *(float4*)&lds[(ry << 6) + 4 * rp] = f;
        }
    }
    __syncthreads();

    // --- compute: thread (xl = tid&31, yl = tid>>5), 8 y-steps of stride 8.
    const int xl = tid & 31;
    const int yl = tid >> 5;
    const int x = tx0 + xl;
    const int ybase = ty0 + yl;

    const float dx = (float)x - T13;
    // i01 == 0 exactly (a = hx - r = 0): sx is y-invariant -> hoist x-path.
    const float sxl = i00 * dx - (float)xs0;
    const float x0f = floorf(sxl);
    const float wx = sxl - x0f;
    const int x0 = (int)x0f;

    float syl = i10 * dx + i11 * ((float)ybase - T23) - (float)ys0;
    const float dsy = 8.0f * i11;

    float* po = out + ((size_t)b * 3 + c) * plane + (size_t)ybase * W + x;

    if ((tx0 + TW <= W) & (ty0 + TH <= H)) {   // full tile (always, here)
        #pragma unroll
        for (int k = 0; k < TH / 8; ++k) {
            const float y0f = floorf(syl);
            const float wy = syl - y0f;
            const int y0 = (int)y0f;
            const int iA = (y0 << 6) + x0;
            const float v00 = lds[iA];
            const float v01 = lds[iA + 1];
            const float v10 = lds[iA + PITCH];
            const float v11 = lds[iA + PITCH + 1];
            const float top = v00 + wx * (v01 - v00);
            const float bot = v10 + wx * (v11 - v10);
            __builtin_nontemporal_store(top + wy * (bot - top), po);
            po  += 8 * W;
            syl += dsy;
        }
    } else {                                   // partial tile (generality)
        if (x >= W) return;
        #pragma unroll
        for (int k = 0; k < TH / 8; ++k) {
            const int y = ybase + 8 * k;
            if (y >= H) break;
            const float y0f = floorf(syl);
            const float wy = syl - y0f;
            const int y0 = (int)y0f;
            const int iA = (y0 << 6) + x0;
            const float v00 = lds[iA];
            const float v01 = lds[iA + 1];
            const float v10 = lds[iA + PITCH];
            const float v11 = lds[iA + PITCH + 1];
            const float top = v00 + wx * (v01 - v00);
            const float bot = v10 + wx * (v11 - v10);
            __builtin_nontemporal_store(top + wy * (bot - top), po);
            po  += 8 * W;
            syl += dsy;
        }
    }
}

extern "C" void kernel_launch(void* const* d_in, const int* in_sizes, int n_in,
                              void* d_out, int out_size, void* d_ws, size_t ws_size,
                              hipStream_t stream) {
    const float* img = (const float*)d_in[0];
    const float* rnd = (const float*)d_in[1];
    float* out = (float*)d_out;
    float* params = (float*)d_ws;

    const int B = in_sizes[1];            // 128
    const int C = 3;
    const int total = in_sizes[0];        // B*C*H*W
    const int HW = total / (B * C);       // 65536
    int W = 256;                          // square images
    while (W * W > HW) W >>= 1;
    const int H = HW / W;

    const int tilesX = (W + TW - 1) / TW;     // 8 (pow2 for W=256)
    const int tilesY = (H + TH - 1) / TH;     // 4
    const int nTile = tilesX * tilesY;        // 32
    int tilesXShift = 0;
    while ((1 << tilesXShift) < tilesX) ++tilesXShift;

    // ws layout: params (B*6 floats) | bbox (B*nTile int4), 16B-aligned
    int4* bbox = (int4*)((char*)d_ws + ((B * 6 * sizeof(float) + 15) & ~15));

    const int nPar = B * nTile;
    TCR_params_kernel<<<(nPar + 255) / 256, 256, 0, stream>>>(
        rnd, params, bbox, B, W, H, tilesX, nTile);

    dim3 grid(B, nTile, C);
    TCR_warp_kernel<<<grid, 256, 0, stream>>>(img, params, bbox, out,
                                              H, W, tilesXShift);
}

// Round 9
// 41.499 us; speedup vs baseline: 1.3403x; 1.0230x over previous
//
#include <hip/hip_runtime.h>
#include <math.h>

// Affine warp augmentation (kornia-style warp_affine, bilinear, zeros padding,
// align_corners pixel coords). B=128, C=3, H=W=256, fp32.
//
// R9: R8 with nontemporal stores REMOVED (single-variable change).
// Theory: in the timed graph-replay regime the input (100.7 MB) is
// L3-resident and d_out is the SAME 98.3 MB region every replay. NT stores
// bypass L3 and force a full HBM write per replay; plain write-back stores
// let the Infinity Cache absorb the rewrites (dirty lines are overwritten by
// the next replay before eviction), collapsing steady-state HBM traffic.
// Input+output = 199 MB < 256 MB L3.
//
// Carried from R8:
//  - PITCH=64: gather bank = x0%32, ~conflict-free for every angle; staging
//    via single ds_write_b128 per 4-float slot.
//  - i01 == 0 exactly (a = hx-r = 0) -> sx/x0/wx hoisted out of the y-loop.
//  - Per-(b,tile) bbox precomputed in params kernel; 3D grid (B,nTile,C) ->
//    no divides in hot kernel; gridDim.x=128 = 0 mod 8 pins each image's
//    blocks to one XCD.
//  - float4 zero-halo staging with fast interior path; mask-free bilinear
//    inner loop (zero-halo reproduces zeros-padding exactly).

#define AUG_ANG 0.34906585039886590  // deg2rad(20)
#define AUG_MAX_T 6.0

#define TW 32
#define TH 64
#define PITCH 64       // power-of-2: bank = x0 % 32 (y0 vanishes); b128-aligned
#define MAXROWS 108    // >= |i10|*31 + i11*63 + 5 = 24.5+77.3+5
#define SLOTS 10       // staged float4 slots per row (40 floats >= ws 38)

// One thread per (b, tile): builds the per-b affine params (thread with
// tile==0 writes them) and the per-(b,tile) source bbox.
__global__ void TCR_params_kernel(const float* __restrict__ rnd,
                                  float* __restrict__ p,
                                  int4* __restrict__ bb,
                                  int B, int W, int H,
                                  int tilesX, int nTile) {
    const int idx = blockIdx.x * blockDim.x + threadIdx.x;
    if (idx >= B * nTile) return;
    const int b = idx / nTile;
    const int t = idx - b * nTile;

    double r01 = (double)rnd[b];
    double tx = 2.0 * AUG_MAX_T * r01 - AUG_MAX_T;
    double ty = tx;                       // same random tensor for all params
    double r  = 2.0 * AUG_ANG * r01 - AUG_ANG;
    double z  = 1.0;                      // MAX_Z == MIN_Z == 1
    double hx = r, hy = r;
    double a  = hx - r;                   // == 0 exactly
    double bbang = hy + r;
    double cos_hx = cos(hx), cos_hy = cos(hy);
    double ca = cos(a),  sa = sin(a);
    double cb = cos(bbang), sb = sin(bbang);
    double T11 = z * ca / cos_hx;
    double T12 = z * sa / cos_hx;
    double T13 = ((double)W * cos_hx - (double)W * z * ca + 2.0 * tx * z * ca
                  - (double)H * z * sa + 2.0 * ty * z * sa) / (2.0 * cos_hx);
    double T21 = z * sb / cos_hy;
    double T22 = z * cb / cos_hy;
    double T23 = ((double)H * cos_hy - (double)W * z * cb + 2.0 * ty * z * cb
                  - (double)W * z * sb + 2.0 * tx * z * sb) / (2.0 * cos_hy);
    double det = T11 * T22 - T12 * T21;
    const float i00 = (float)( T22 / det);
    const float i01 = (float)(-T12 / det);   // == +/-0
    const float i10 = (float)(-T21 / det);
    const float i11 = (float)( T11 / det);
    const float f13 = (float)T13;
    const float f23 = (float)T23;

    if (t == 0) {
        p[b * 6 + 0] = i00;
        p[b * 6 + 1] = i01;
        p[b * 6 + 2] = i10;
        p[b * 6 + 3] = i11;
        p[b * 6 + 4] = f13;
        p[b * 6 + 5] = f23;
    }

    // bbox for tile t (float corner math, +/-1 margins; corners bound the
    // interior of an affine map)
    const int tileY = t / tilesX, tileX = t - tileY * tilesX;
    const int tx0 = tileX * TW, ty0 = tileY * TH;
    const int tx1 = min(tx0 + TW - 1, W - 1);
    const int ty1 = min(ty0 + TH - 1, H - 1);
    const float cx0 = (float)tx0 - f13, cx1 = (float)tx1 - f13;
    const float cy0 = (float)ty0 - f23, cy1 = (float)ty1 - f23;
    const float sxA = i00 * cx0 + i01 * cy0, sxB = i00 * cx1 + i01 * cy0;
    const float sxC = i00 * cx0 + i01 * cy1, sxD = i00 * cx1 + i01 * cy1;
    const float syA = i10 * cx0 + i11 * cy0, syB = i10 * cx1 + i11 * cy0;
    const float syC = i10 * cx0 + i11 * cy1, syD = i10 * cx1 + i11 * cy1;
    const float sxmin = fminf(fminf(sxA, sxB), fminf(sxC, sxD));
    const float symin = fminf(fminf(syA, syB), fminf(syC, syD));
    const float symax = fmaxf(fmaxf(syA, syB), fmaxf(syC, syD));
    const int xs0 = ((int)floorf(sxmin) - 1) & ~3;     // 4-aligned down
    const int ys0 = (int)floorf(symin) - 1;
    const int ys1 = min((int)floorf(symax) + 2, ys0 + MAXROWS - 1);
    int4 v; v.x = xs0; v.y = ys0; v.z = ys1 - ys0 + 1; v.w = 0;
    bb[idx] = v;
}

// Grid: (B, nTile, C). Block: 256 threads.
__global__ __launch_bounds__(256) void TCR_warp_kernel(
        const float* __restrict__ img, const float* __restrict__ p,
        const int4* __restrict__ bb, float* __restrict__ out,
        int H, int W, int tilesXShift) {
    __shared__ float lds[MAXROWS * PITCH + 4];

    const int tid = (int)threadIdx.x;
    const int b = (int)blockIdx.x;
    const int t = (int)blockIdx.y;
    const int c = (int)blockIdx.z;
    const int nTile = (int)gridDim.y;
    const int tileY = t >> tilesXShift;
    const int tileX = t - (tileY << tilesXShift);
    const int tx0 = tileX * TW, ty0 = tileY * TH;

    const int4 box = bb[b * nTile + t];
    const int xs0 = box.x, ys0 = box.y, hs = box.z;

    const float i00 = p[b * 6 + 0];
    const float i10 = p[b * 6 + 2];
    const float i11 = p[b * 6 + 3];
    const float T13 = p[b * 6 + 4];
    const float T23 = p[b * 6 + 5];

    const size_t plane = (size_t)H * W;
    const float* pl = img + ((size_t)b * 3 + c) * plane;

    // --- stage rows [ys0, ys0+hs) x cols [xs0, xs0+40) with zero-halo.
    // One ds_write_b128 per slot (o = ry*64 + 4*rp is 16B-aligned).
    const int nTask = hs * SLOTS;
    const bool fast = (xs0 >= 0) & (xs0 + 4 * SLOTS <= W) &
                      (ys0 >= 0) & (ys0 + hs <= H);
    if (fast) {
        for (int j = tid; j < nTask; j += 256) {
            const int ry = (int)((unsigned)j / SLOTS);   // literal -> magic mul
            const int rp = j - ry * SLOTS;
            const float4 f =
                *(const float4*)(pl + (size_t)(ys0 + ry) * W + xs0 + 4 * rp);
            *(float4*)&lds[(ry << 6) + 4 * rp] = f;
        }
    } else {
        for (int j = tid; j < nTask; j += 256) {
            const int ry = (int)((unsigned)j / SLOTS);
            const int rp = j - ry * SLOTS;
            const int gy = ys0 + ry;
            const int gx = xs0 + 4 * rp;
            const int gyc = min(max(gy, 0), H - 1);
            const int gxc = min(max(gx, 0), W - 4);
            float4 f = *(const float4*)(pl + (size_t)gyc * W + gxc);
            // whole-slot validity: xs0 and W are multiples of 4, so a slot is
            // fully inside or fully outside in x.
            const bool ok = ((unsigned)gy < (unsigned)H) &
                            ((unsigned)gx < (unsigned)W);
            f.x = ok ? f.x : 0.0f;
            f.y = ok ? f.y : 0.0f;
            f.z = ok ? f.z : 0.0f;
            f.w = ok ? f.w : 0.0f;
            *(float4*)&lds[(ry << 6) + 4 * rp] = f;
        }
    }
    __syncthreads();

    // --- compute: thread (xl = tid&31, yl = tid>>5), 8 y-steps of stride 8.
    const int xl = tid & 31;
    const int yl = tid >> 5;
    const int x = tx0 + xl;
    const int ybase = ty0 + yl;

    const float dx = (float)x - T13;
    // i01 == 0 exactly (a = hx - r = 0): sx is y-invariant -> hoist x-path.
    const float sxl = i00 * dx - (float)xs0;
    const float x0f = floorf(sxl);
    const float wx = sxl - x0f;
    const int x0 = (int)x0f;

    float syl = i10 * dx + i11 * ((float)ybase - T23) - (float)ys0;
    const float dsy = 8.0f * i11;

    float* po = out + ((size_t)b * 3 + c) * plane + (size_t)ybase * W + x;

    if ((tx0 + TW <= W) & (ty0 + TH <= H)) {   // full tile (always, here)
        #pragma unroll
        for (int k = 0; k < TH / 8; ++k) {
            const float y0f = floorf(syl);
            const float wy = syl - y0f;
            const int y0 = (int)y0f;
            const int iA = (y0 << 6) + x0;
            const float v00 = lds[iA];
            const float v01 = lds[iA + 1];
            const float v10 = lds[iA + PITCH];
            const float v11 = lds[iA + PITCH + 1];
            const float top = v00 + wx * (v01 - v00);
            const float bot = v10 + wx * (v11 - v10);
            *po = top + wy * (bot - top);
            po  += 8 * W;
            syl += dsy;
        }
    } else {                                   // partial tile (generality)
        if (x >= W) return;
        #pragma unroll
        for (int k = 0; k < TH / 8; ++k) {
            const int y = ybase + 8 * k;
            if (y >= H) break;
            const float y0f = floorf(syl);
            const float wy = syl - y0f;
            const int y0 = (int)y0f;
            const int iA = (y0 << 6) + x0;
            const float v00 = lds[iA];
            const float v01 = lds[iA + 1];
            const float v10 = lds[iA + PITCH];
            const float v11 = lds[iA + PITCH + 1];
            const float top = v00 + wx * (v01 - v00);
            const float bot = v10 + wx * (v11 - v10);
            *po = top + wy * (bot - top);
            po  += 8 * W;
            syl += dsy;
        }
    }
}

extern "C" void kernel_launch(void* const* d_in, const int* in_sizes, int n_in,
                              void* d_out, int out_size, void* d_ws, size_t ws_size,
                              hipStream_t stream) {
    const float* img = (const float*)d_in[0];
    const float* rnd = (const float*)d_in[1];
    float* out = (float*)d_out;
    float* params = (float*)d_ws;

    const int B = in_sizes[1];            // 128
    const int C = 3;
    const int total = in_sizes[0];        // B*C*H*W
    const int HW = total / (B * C);       // 65536
    int W = 256;                          // square images
    while (W * W > HW) W >>= 1;
    const int H = HW / W;

    const int tilesX = (W + TW - 1) / TW;     // 8 (pow2 for W=256)
    const int tilesY = (H + TH - 1) / TH;     // 4
    const int nTile = tilesX * tilesY;        // 32
    int tilesXShift = 0;
    while ((1 << tilesXShift) < tilesX) ++tilesXShift;

    // ws layout: params (B*6 floats) | bbox (B*nTile int4), 16B-aligned
    int4* bbox = (int4*)((char*)d_ws + ((B * 6 * sizeof(float) + 15) & ~15));

    const int nPar = B * nTile;
    TCR_params_kernel<<<(nPar + 255) / 256, 256, 0, stream>>>(
        rnd, params, bbox, B, W, H, tilesX, nTile);

    dim3 grid(B, nTile, C);
    TCR_warp_kernel<<<grid, 256, 0, stream>>>(img, params, bbox, out,
                                              H, W, tilesXShift);
}